// Round 1
// baseline (19698.412 us; speedup 1.0000x reference)
//
#include <hip/hip_runtime.h>
#include <math.h>

#define B_ROWS 65536
#define D_IN   784
#define D_HID  512
#define D_LAT  256
#define N_CODES 256

#define BK   16
// f64 path tile (8x4 per thread)
#define BM64 128
#define BN64 64
// f32 path tile (8x8 per thread)
#define BM32 128
#define BN32 128

// ---------- u64 argmin key: ordered f64 bits, low 8 bits = code ----------
__device__ __forceinline__ unsigned long long enc_key(double d, int code) {
    unsigned long long u = (unsigned long long)__double_as_longlong(d);
    u = (u & 0x8000000000000000ull) ? ~u : (u | 0x8000000000000000ull);
    return (u & ~0xFFull) | (unsigned long long)code;
}
__device__ __forceinline__ double dec_key(unsigned long long k) {
    k &= ~0xFFull;
    k = (k & 0x8000000000000000ull) ? (k ^ 0x8000000000000000ull) : ~k;
    return __longlong_as_double((long long)k);
}

// ---------------- f64-accumulate GEMM (encoder path), 8x4, double-buffered ----------------
template<int ACT>
__global__ __launch_bounds__(256, 4)
void gemm_f64_kernel(const float* __restrict__ A, const float* __restrict__ W,
                     const float* __restrict__ bias, float* __restrict__ C,
                     int M, int N, int K)
{
    __shared__ float As[2][BK][BM64 + 4];
    __shared__ float Bs[2][BK][BN64 + 4];

    const int tid  = threadIdx.x;
    const int row0 = blockIdx.y * BM64;
    const int col0 = blockIdx.x * BN64;
    const int tx = tid & 15;        // 4 output cols each
    const int ty = tid >> 4;        // 8 output rows each

    // A staging: 128 rows x 16 k = 512 float4 -> 2 per thread
    const int a_r = tid >> 2;            // 0..63 (and +64)
    const int a_c = (tid & 3) << 2;      // k offset 0,4,8,12
    // B staging: 16 k x 64 n = 256 float4 -> 1 per thread
    const int b_r = tid >> 4;            // k 0..15
    const int b_c = (tid & 15) << 2;     // n offset

    const float* Arow0 = A + (size_t)(row0 + a_r) * K + a_c;
    const float* Arow1 = A + (size_t)(row0 + 64 + a_r) * K + a_c;
    const float* Wrow  = W + (size_t)b_r * N + col0 + b_c;

    double acc[8][4] = {};

    // prologue: stage tile 0 into buffer 0
    {
        const float4 av0 = *(const float4*)(Arow0);
        const float4 av1 = *(const float4*)(Arow1);
        const float4 bv  = *(const float4*)(Wrow);
        As[0][a_c + 0][a_r] = av0.x; As[0][a_c + 1][a_r] = av0.y;
        As[0][a_c + 2][a_r] = av0.z; As[0][a_c + 3][a_r] = av0.w;
        As[0][a_c + 0][64 + a_r] = av1.x; As[0][a_c + 1][64 + a_r] = av1.y;
        As[0][a_c + 2][64 + a_r] = av1.z; As[0][a_c + 3][64 + a_r] = av1.w;
        *(float4*)&Bs[0][b_r][b_c] = bv;
    }
    __syncthreads();

    int cur = 0;
    for (int k0 = 0; k0 < K; k0 += BK) {
        const int kn = k0 + BK;
        float4 av0, av1, bv;
        if (kn < K) {                       // issue next-tile loads early
            av0 = *(const float4*)(Arow0 + kn);
            av1 = *(const float4*)(Arow1 + kn);
            bv  = *(const float4*)(Wrow + (size_t)kn * N);
        }

        #pragma unroll
        for (int kk = 0; kk < BK; ++kk) {
            const float4 a0 = *(const float4*)&As[cur][kk][ty << 3];
            const float4 a1 = *(const float4*)&As[cur][kk][(ty << 3) + 4];
            const float4 b  = *(const float4*)&Bs[cur][kk][tx << 2];
            const double ad[8] = {(double)a0.x, (double)a0.y, (double)a0.z, (double)a0.w,
                                  (double)a1.x, (double)a1.y, (double)a1.z, (double)a1.w};
            const double bd[4] = {(double)b.x, (double)b.y, (double)b.z, (double)b.w};
            #pragma unroll
            for (int i = 0; i < 8; ++i)
                #pragma unroll
                for (int j = 0; j < 4; ++j)
                    acc[i][j] = fma(ad[i], bd[j], acc[i][j]);
        }

        if (kn < K) {
            const int nb = cur ^ 1;
            As[nb][a_c + 0][a_r] = av0.x; As[nb][a_c + 1][a_r] = av0.y;
            As[nb][a_c + 2][a_r] = av0.z; As[nb][a_c + 3][a_r] = av0.w;
            As[nb][a_c + 0][64 + a_r] = av1.x; As[nb][a_c + 1][64 + a_r] = av1.y;
            As[nb][a_c + 2][64 + a_r] = av1.z; As[nb][a_c + 3][64 + a_r] = av1.w;
            *(float4*)&Bs[nb][b_r][b_c] = bv;
            __syncthreads();
            cur = nb;
        }
    }

    const int cbase = col0 + (tx << 2);
    const double bb0 = (double)bias[cbase + 0];
    const double bb1 = (double)bias[cbase + 1];
    const double bb2 = (double)bias[cbase + 2];
    const double bb3 = (double)bias[cbase + 3];
    #pragma unroll
    for (int i = 0; i < 8; ++i) {
        const int r = row0 + (ty << 3) + i;
        double v0 = acc[i][0] + bb0;
        double v1 = acc[i][1] + bb1;
        double v2 = acc[i][2] + bb2;
        double v3 = acc[i][3] + bb3;
        if (ACT == 1) {
            v0 = fmax(v0, 0.0); v1 = fmax(v1, 0.0);
            v2 = fmax(v2, 0.0); v3 = fmax(v3, 0.0);
        }
        const float4 o = make_float4((float)v0, (float)v1, (float)v2, (float)v3);
        *(float4*)(C + (size_t)r * N + cbase) = o;
    }
}

// ---------------- codebook squared norms (f64) ----------------
__global__ void cnorm_kernel(const float* __restrict__ cb0, const float* __restrict__ cb1,
                             double* __restrict__ cn0, double* __restrict__ cn1)
{
    const float* cb = blockIdx.x ? cb1 : cb0;
    double* cn      = blockIdx.x ? cn1 : cn0;
    const int j = threadIdx.x;
    const float* row = cb + (size_t)j * D_LAT;
    double s = 0.0;
    #pragma unroll 8
    for (int t = 0; t < 64; ++t) {
        const float4 c = *(const float4*)(row + (t << 2));
        s = fma((double)c.x, (double)c.x, s);
        s = fma((double)c.y, (double)c.y, s);
        s = fma((double)c.z, (double)c.z, s);
        s = fma((double)c.w, (double)c.w, s);
    }
    cn[j] = s;
}

// ---------------- VQ distance GEMM pass (f64), 8x4, double-buffered ----------------
template<bool SUB>
__global__ __launch_bounds__(256, 4)
void vq_dots_kernel(const float* __restrict__ enc, const float* __restrict__ cbA,
                    const unsigned long long* __restrict__ key_in,
                    const float* __restrict__ cb, const double* __restrict__ cnorm,
                    unsigned long long* __restrict__ key_out)
{
    __shared__ float As[2][BK][BM64 + 4];
    __shared__ float Bs[2][BK][BN64 + 4];

    const int tid   = threadIdx.x;
    const int row0  = blockIdx.y * BM64;
    const int code0 = blockIdx.x * BN64;
    const int tx = tid & 15;
    const int ty = tid >> 4;
    const int a_r = tid >> 2;
    const int a_c = (tid & 3) << 2;

    int sub0 = 0, sub1 = 0;
    if (SUB) {
        sub0 = (int)(key_in[row0 + a_r] & 0xFFull);
        sub1 = (int)(key_in[row0 + 64 + a_r] & 0xFFull);
    }
    const float* Er0 = enc + (size_t)(row0 + a_r) * D_LAT + a_c;
    const float* Er1 = enc + (size_t)(row0 + 64 + a_r) * D_LAT + a_c;
    const float* Q0  = SUB ? (cbA + (size_t)sub0 * D_LAT + a_c) : nullptr;
    const float* Q1  = SUB ? (cbA + (size_t)sub1 * D_LAT + a_c) : nullptr;
    const float* Cbr = cb + (size_t)(code0 + a_r) * D_LAT + a_c;   // transpose-staged

    double acc[8][4] = {};

    // prologue stage (k=0)
    {
        float4 av0 = *(const float4*)(Er0);
        float4 av1 = *(const float4*)(Er1);
        if (SUB) {
            const float4 q0 = *(const float4*)(Q0);
            const float4 q1 = *(const float4*)(Q1);
            av0.x -= q0.x; av0.y -= q0.y; av0.z -= q0.z; av0.w -= q0.w;
            av1.x -= q1.x; av1.y -= q1.y; av1.z -= q1.z; av1.w -= q1.w;
        }
        const float4 bv = *(const float4*)(Cbr);
        As[0][a_c + 0][a_r] = av0.x; As[0][a_c + 1][a_r] = av0.y;
        As[0][a_c + 2][a_r] = av0.z; As[0][a_c + 3][a_r] = av0.w;
        As[0][a_c + 0][64 + a_r] = av1.x; As[0][a_c + 1][64 + a_r] = av1.y;
        As[0][a_c + 2][64 + a_r] = av1.z; As[0][a_c + 3][64 + a_r] = av1.w;
        Bs[0][a_c + 0][a_r] = bv.x; Bs[0][a_c + 1][a_r] = bv.y;
        Bs[0][a_c + 2][a_r] = bv.z; Bs[0][a_c + 3][a_r] = bv.w;
    }
    __syncthreads();

    int cur = 0;
    for (int k0 = 0; k0 < D_LAT; k0 += BK) {
        const int kn = k0 + BK;
        float4 av0, av1, bv;
        if (kn < D_LAT) {
            av0 = *(const float4*)(Er0 + kn);
            av1 = *(const float4*)(Er1 + kn);
            if (SUB) {
                const float4 q0 = *(const float4*)(Q0 + kn);
                const float4 q1 = *(const float4*)(Q1 + kn);
                av0.x -= q0.x; av0.y -= q0.y; av0.z -= q0.z; av0.w -= q0.w;
                av1.x -= q1.x; av1.y -= q1.y; av1.z -= q1.z; av1.w -= q1.w;
            }
            bv = *(const float4*)(Cbr + kn);
        }

        #pragma unroll
        for (int kk = 0; kk < BK; ++kk) {
            const float4 a0 = *(const float4*)&As[cur][kk][ty << 3];
            const float4 a1 = *(const float4*)&As[cur][kk][(ty << 3) + 4];
            const float4 b  = *(const float4*)&Bs[cur][kk][tx << 2];
            const double ad[8] = {(double)a0.x, (double)a0.y, (double)a0.z, (double)a0.w,
                                  (double)a1.x, (double)a1.y, (double)a1.z, (double)a1.w};
            const double bd[4] = {(double)b.x, (double)b.y, (double)b.z, (double)b.w};
            #pragma unroll
            for (int i = 0; i < 8; ++i)
                #pragma unroll
                for (int j = 0; j < 4; ++j)
                    acc[i][j] = fma(ad[i], bd[j], acc[i][j]);
        }

        if (kn < D_LAT) {
            const int nb = cur ^ 1;
            As[nb][a_c + 0][a_r] = av0.x; As[nb][a_c + 1][a_r] = av0.y;
            As[nb][a_c + 2][a_r] = av0.z; As[nb][a_c + 3][a_r] = av0.w;
            As[nb][a_c + 0][64 + a_r] = av1.x; As[nb][a_c + 1][64 + a_r] = av1.y;
            As[nb][a_c + 2][64 + a_r] = av1.z; As[nb][a_c + 3][64 + a_r] = av1.w;
            Bs[nb][a_c + 0][a_r] = bv.x; Bs[nb][a_c + 1][a_r] = bv.y;
            Bs[nb][a_c + 2][a_r] = bv.z; Bs[nb][a_c + 3][a_r] = bv.w;
            __syncthreads();
            cur = nb;
        }
    }

    // epilogue: per-thread min over 4 codes, butterfly-min across the 16 tx lanes
    unsigned long long kmin[8];
    #pragma unroll
    for (int i = 0; i < 8; ++i) {
        kmin[i] = 0xFFFFFFFFFFFFFFFFull;
        #pragma unroll
        for (int j = 0; j < 4; ++j) {
            const int code = code0 + (tx << 2) + j;
            const double d = cnorm[code] - 2.0 * acc[i][j];
            const unsigned long long k = enc_key(d, code);
            if (k < kmin[i]) kmin[i] = k;
        }
    }
    #pragma unroll
    for (int off = 1; off < 16; off <<= 1) {
        #pragma unroll
        for (int i = 0; i < 8; ++i) {
            const unsigned long long o = __shfl_xor(kmin[i], off, 64);
            if (o < kmin[i]) kmin[i] = o;
        }
    }
    if (tx == 0) {
        #pragma unroll
        for (int i = 0; i < 8; ++i)
            atomicMin(key_out + row0 + (ty << 3) + i, kmin[i]);
    }
}

// ---------------- f32 GEMM (decoder path), 8x8, double-buffered ----------------
// cols per thread are STRIDED (c = col0 + j*16 + tx) -> conflict-free scalar
// B-fragment reads (16 lanes hit 16 distinct banks) and coalesced C stores.
template<int ACT, bool FUSE_LOSS>   // ACT: 0=none,1=relu,2=tanh
__global__ __launch_bounds__(256, 4)
void gemm_kernel(const float* __restrict__ A, const float* __restrict__ W,
                 const float* __restrict__ bias, float* __restrict__ C,
                 const float* __restrict__ X, float* __restrict__ loss_acc,
                 int M, int N, int K)
{
    __shared__ float As[2][BK][BM32 + 4];
    __shared__ float Bs[2][BK][BN32 + 4];
    __shared__ float wsum[4];

    const int tid  = threadIdx.x;
    const int row0 = blockIdx.y * BM32;
    const int col0 = blockIdx.x * BN32;
    const int tx = tid & 15;
    const int ty = tid >> 4;

    const int a_r = tid >> 2;
    const int a_c = (tid & 3) << 2;
    const int b_r = tid >> 4;            // k 0..15
    const int b_c = (tid & 15) << 3;     // n offset, 8 floats per thread (2 float4)

    const float* Arow0 = A + (size_t)(row0 + a_r) * K + a_c;
    const float* Arow1 = A + (size_t)(row0 + 64 + a_r) * K + a_c;

    float acc[8][8] = {};

    // B tile loader with N-guard (N=784 tail block)
    auto loadB = [&](int k, float4& b0, float4& b1) {
        const int gc = col0 + b_c;
        const float* Wr = W + (size_t)(k + b_r) * N + gc;
        if (gc + 7 < N) {
            b0 = *(const float4*)(Wr);
            b1 = *(const float4*)(Wr + 4);
        } else {
            float t[8];
            #pragma unroll
            for (int u = 0; u < 8; ++u) t[u] = (gc + u < N) ? Wr[u] : 0.f;
            b0 = make_float4(t[0], t[1], t[2], t[3]);
            b1 = make_float4(t[4], t[5], t[6], t[7]);
        }
    };

    // prologue
    {
        const float4 av0 = *(const float4*)(Arow0);
        const float4 av1 = *(const float4*)(Arow1);
        float4 bv0, bv1; loadB(0, bv0, bv1);
        As[0][a_c + 0][a_r] = av0.x; As[0][a_c + 1][a_r] = av0.y;
        As[0][a_c + 2][a_r] = av0.z; As[0][a_c + 3][a_r] = av0.w;
        As[0][a_c + 0][64 + a_r] = av1.x; As[0][a_c + 1][64 + a_r] = av1.y;
        As[0][a_c + 2][64 + a_r] = av1.z; As[0][a_c + 3][64 + a_r] = av1.w;
        *(float4*)&Bs[0][b_r][b_c] = bv0;
        *(float4*)&Bs[0][b_r][b_c + 4] = bv1;
    }
    __syncthreads();

    int cur = 0;
    for (int k0 = 0; k0 < K; k0 += BK) {
        const int kn = k0 + BK;
        float4 av0, av1, bv0, bv1;
        if (kn < K) {
            av0 = *(const float4*)(Arow0 + kn);
            av1 = *(const float4*)(Arow1 + kn);
            loadB(kn, bv0, bv1);
        }

        #pragma unroll
        for (int kk = 0; kk < BK; ++kk) {
            const float4 a0 = *(const float4*)&As[cur][kk][ty << 3];
            const float4 a1 = *(const float4*)&As[cur][kk][(ty << 3) + 4];
            const float ar[8] = {a0.x, a0.y, a0.z, a0.w, a1.x, a1.y, a1.z, a1.w};
            float br[8];
            #pragma unroll
            for (int j = 0; j < 8; ++j)
                br[j] = Bs[cur][kk][(j << 4) + tx];
            #pragma unroll
            for (int i = 0; i < 8; ++i)
                #pragma unroll
                for (int j = 0; j < 8; ++j)
                    acc[i][j] = fmaf(ar[i], br[j], acc[i][j]);
        }

        if (kn < K) {
            const int nb = cur ^ 1;
            As[nb][a_c + 0][a_r] = av0.x; As[nb][a_c + 1][a_r] = av0.y;
            As[nb][a_c + 2][a_r] = av0.z; As[nb][a_c + 3][a_r] = av0.w;
            As[nb][a_c + 0][64 + a_r] = av1.x; As[nb][a_c + 1][64 + a_r] = av1.y;
            As[nb][a_c + 2][64 + a_r] = av1.z; As[nb][a_c + 3][64 + a_r] = av1.w;
            *(float4*)&Bs[nb][b_r][b_c] = bv0;
            *(float4*)&Bs[nb][b_r][b_c + 4] = bv1;
            __syncthreads();
            cur = nb;
        }
    }

    // epilogue
    float bb[8];
    #pragma unroll
    for (int j = 0; j < 8; ++j) {
        const int c = col0 + (j << 4) + tx;
        bb[j] = (c < N) ? bias[c] : 0.f;
    }

    float lsum = 0.f;
    #pragma unroll
    for (int i = 0; i < 8; ++i) {
        const int r = row0 + (ty << 3) + i;
        #pragma unroll
        for (int j = 0; j < 8; ++j) {
            const int c = col0 + (j << 4) + tx;
            if (c < N) {
                float v = acc[i][j] + bb[j];
                if (ACT == 1) v = fmaxf(v, 0.f);
                if (ACT == 2) v = tanhf(v);
                C[(size_t)r * N + c] = v;
                if (FUSE_LOSS) {
                    const float d = v - X[(size_t)r * N + c];
                    lsum = fmaf(d, d, lsum);
                }
            }
        }
    }

    if (FUSE_LOSS) {
        #pragma unroll
        for (int off = 32; off > 0; off >>= 1)
            lsum += __shfl_xor(lsum, off, 64);
        if ((tid & 63) == 0) wsum[tid >> 6] = lsum;
        __syncthreads();
        if (tid == 0)
            atomicAdd(loss_acc, wsum[0] + wsum[1] + wsum[2] + wsum[3]);
    }
}

// ---------------- VQ finalize: indices, commit, quantized ----------------
__global__ __launch_bounds__(256)
void vq_finalize_kernel(float* __restrict__ encq,
                        const float* __restrict__ cb0, const float* __restrict__ cb1,
                        const unsigned long long* __restrict__ key0,
                        const unsigned long long* __restrict__ key1,
                        float* __restrict__ idx_out, float* __restrict__ commit_acc)
{
    __shared__ float csum[4];
    const int wave = threadIdx.x >> 6;
    const int lane = threadIdx.x & 63;
    const int row  = (blockIdx.x << 2) + wave;

    const unsigned long long k0 = key0[row];
    const unsigned long long k1 = key1[row];
    const int i0 = (int)(k0 & 0xFFull);
    const int i1 = (int)(k1 & 0xFFull);

    const float4 e = *(const float4*)(encq + (size_t)row * D_LAT + (lane << 2));
    float nrm = 0.f;
    nrm = fmaf(e.x, e.x, nrm); nrm = fmaf(e.y, e.y, nrm);
    nrm = fmaf(e.z, e.z, nrm); nrm = fmaf(e.w, e.w, nrm);
    #pragma unroll
    for (int off = 32; off > 0; off >>= 1)
        nrm += __shfl_xor(nrm, off, 64);

    const float4 q0 = *(const float4*)(cb0 + (size_t)i0 * D_LAT + (lane << 2));
    const float4 q1 = *(const float4*)(cb1 + (size_t)i1 * D_LAT + (lane << 2));
    const float4 q = make_float4(q0.x + q1.x, q0.y + q1.y, q0.z + q1.z, q0.w + q1.w);
    *(float4*)(encq + (size_t)row * D_LAT + (lane << 2)) = q;

    if (lane == 0) {
        idx_out[(size_t)row * 2 + 0] = (float)i0;
        idx_out[(size_t)row * 2 + 1] = (float)i1;
        const float d0 = (float)dec_key(k0);
        const float d1 = (float)dec_key(k1);
        csum[wave] = 2.f * (nrm + d0) + d1;
    }
    __syncthreads();
    if (threadIdx.x == 0)
        atomicAdd(commit_acc, csum[0] + csum[1] + csum[2] + csum[3]);
}

__global__ void finalize_kernel(const float* __restrict__ acc, float* __restrict__ out_loss)
{
    const float recon_loss  = acc[0] / (float)((size_t)B_ROWS * D_IN);
    const float commit_loss = 0.25f * acc[1] / (float)((size_t)B_ROWS * D_LAT);
    *out_loss = recon_loss + commit_loss;
}

extern "C" void kernel_launch(void* const* d_in, const int* in_sizes, int n_in,
                              void* d_out, int out_size, void* d_ws, size_t ws_size,
                              hipStream_t stream)
{
    const float* x   = (const float*)d_in[0];
    const float* We1 = (const float*)d_in[1];
    const float* be1 = (const float*)d_in[2];
    const float* We2 = (const float*)d_in[3];
    const float* be2 = (const float*)d_in[4];
    const float* cb0 = (const float*)d_in[5];
    const float* cb1 = (const float*)d_in[6];
    const float* Wd1 = (const float*)d_in[7];
    const float* bd1 = (const float*)d_in[8];
    const float* Wd2 = (const float*)d_in[9];
    const float* bd2 = (const float*)d_in[10];

    float* out      = (float*)d_out;
    float* recon    = out;                                   // B*784
    float* idx_out  = out + (size_t)B_ROWS * D_IN;           // B*2 (as float)
    float* loss_out = idx_out + (size_t)B_ROWS * 2;          // 1

    // ws layout
    char* w = (char*)d_ws;
    float* h = (float*)w;                    w += (size_t)B_ROWS * D_HID * sizeof(float);
    float* acc = (float*)w;                  w += 16;
    unsigned long long* key0 = (unsigned long long*)w;  w += (size_t)B_ROWS * 8;
    unsigned long long* key1 = (unsigned long long*)w;  w += (size_t)B_ROWS * 8;
    double* cn0 = (double*)w;                w += N_CODES * sizeof(double);
    double* cn1 = (double*)w;                w += N_CODES * sizeof(double);

    // enc/quantized live in the recon region of d_out (dead before recon write)
    float* encq = recon;

    hipMemsetAsync(acc, 0, 2 * sizeof(float), stream);
    hipMemsetAsync(key0, 0xFF, (size_t)B_ROWS * 16, stream);   // key0 + key1

    const dim3 blk(256);
    // codebook norms (f64)
    cnorm_kernel<<<dim3(2), blk, 0, stream>>>(cb0, cb1, cn0, cn1);
    // encoder 1 (f64 acc): relu(x @ We1 + be1) -> h
    gemm_f64_kernel<1><<<dim3(D_HID / BN64, B_ROWS / BM64), blk, 0, stream>>>(
        x, We1, be1, h, B_ROWS, D_HID, D_IN);
    // encoder 2 (f64 acc): h @ We2 + be2 -> enc
    gemm_f64_kernel<0><<<dim3(D_LAT / BN64, B_ROWS / BM64), blk, 0, stream>>>(
        h, We2, be2, encq, B_ROWS, D_LAT, D_HID);
    // VQ stage 1: distances to cb0, per-row argmin via u64 atomicMin
    vq_dots_kernel<false><<<dim3(N_CODES / BN64, B_ROWS / BM64), blk, 0, stream>>>(
        encq, nullptr, nullptr, cb0, cn0, key0);
    // VQ stage 2: residual (enc - cb0[i0]) vs cb1
    vq_dots_kernel<true><<<dim3(N_CODES / BN64, B_ROWS / BM64), blk, 0, stream>>>(
        encq, cb0, key0, cb1, cn1, key1);
    // finalize: indices, commit partials, quantized (in place)
    vq_finalize_kernel<<<dim3(B_ROWS / 4), blk, 0, stream>>>(
        encq, cb0, cb1, key0, key1, idx_out, acc + 1);
    // decoder 1 (f32): relu(quantized @ Wd1 + bd1) -> h
    gemm_kernel<1, false><<<dim3(D_HID / BN32, B_ROWS / BM32), blk, 0, stream>>>(
        encq, Wd1, bd1, h, nullptr, nullptr, B_ROWS, D_HID, D_LAT);
    // decoder 2 (f32): tanh(h @ Wd2 + bd2) -> recon, fused MSE partials
    gemm_kernel<2, true><<<dim3((D_IN + BN32 - 1) / BN32, B_ROWS / BM32), blk, 0, stream>>>(
        h, Wd2, bd2, recon, x, acc + 0, B_ROWS, D_IN, D_HID);
    finalize_kernel<<<1, 1, 0, stream>>>(acc, loss_out);
}

// Round 2
// 3010.614 us; speedup vs baseline: 6.5430x; 6.5430x over previous
//
#include <hip/hip_runtime.h>
#include <math.h>

#define B_ROWS 65536
#define D_IN   784
#define D_HID  512
#define D_LAT  256
#define N_CODES 256

#define BK   16
// vq path tile (4x4 per thread, round-0 proven)
#define BMV 64
#define BNV 64
// f32 path tile (8x8 per thread)
#define BM32 128
#define BN32 128

typedef double f64x4 __attribute__((ext_vector_type(4)));

// ---------- u64 argmin key: ordered f64 bits, low 8 bits = code ----------
__device__ __forceinline__ unsigned long long enc_key(double d, int code) {
    unsigned long long u = (unsigned long long)__double_as_longlong(d);
    u = (u & 0x8000000000000000ull) ? ~u : (u | 0x8000000000000000ull);
    return (u & ~0xFFull) | (unsigned long long)code;
}
__device__ __forceinline__ double dec_key(unsigned long long k) {
    k &= ~0xFFull;
    k = (k & 0x8000000000000000ull) ? (k ^ 0x8000000000000000ull) : ~k;
    return __longlong_as_double((long long)k);
}

// ---------------- f64 MFMA GEMM (encoder path) ----------------
// 64x64 block tile, 4 waves in 2x2, each wave 32x32 via 2x2 mfma_f64_16x16x4.
// A,B staged in LDS as f64 (cvt once on VALU during staging; MFMA pipe does
// the FLOPs). Double-buffered, one barrier per K-tile.
// Fragment layout (v_mfma_f64_16x16x4_f64):
//   A[m][k]: lane l holds A[l&15][l>>4]   (m = l&15, k = l>>4)
//   B[k][n]: lane l holds B[l>>4][l&15]
//   D[m][n]: lane l reg g holds D[(l>>4)*4+g][l&15]
template<int ACT>
__global__ __launch_bounds__(256)
void gemm_f64_mfma_kernel(const float* __restrict__ A, const float* __restrict__ W,
                          const float* __restrict__ bias, float* __restrict__ C,
                          int M, int N, int K)
{
    __shared__ double Asd[2][64][17];   // [buf][m][k]
    __shared__ double Bsd[2][16][66];   // [buf][k][n]

    const int tid  = threadIdx.x;
    const int row0 = blockIdx.y * 64;
    const int col0 = blockIdx.x * 64;
    const int wave = tid >> 6;
    const int lane = tid & 63;
    const int wm = (wave >> 1) << 5;    // wave row offset within tile
    const int wn = (wave & 1) << 5;     // wave col offset within tile
    const int l15 = lane & 15;
    const int l4  = lane >> 4;

    // staging: A 64x16 floats (1 float4/thread), B 16x64 floats (1 float4/thread)
    const int a_r = tid >> 2;            // m 0..63
    const int a_c = (tid & 3) << 2;      // k 0,4,8,12
    const int b_r = tid >> 4;            // k 0..15
    const int b_c = (tid & 15) << 2;     // n 0..60

    const float* Ar = A + (size_t)(row0 + a_r) * K + a_c;
    const float* Wr = W + (size_t)b_r * N + col0 + b_c;

    f64x4 acc[2][2] = {};

    // prologue: stage tile 0
    {
        const float4 av = *(const float4*)(Ar);
        const float4 bv = *(const float4*)(Wr);
        Asd[0][a_r][a_c + 0] = (double)av.x;
        Asd[0][a_r][a_c + 1] = (double)av.y;
        Asd[0][a_r][a_c + 2] = (double)av.z;
        Asd[0][a_r][a_c + 3] = (double)av.w;
        Bsd[0][b_r][b_c + 0] = (double)bv.x;
        Bsd[0][b_r][b_c + 1] = (double)bv.y;
        Bsd[0][b_r][b_c + 2] = (double)bv.z;
        Bsd[0][b_r][b_c + 3] = (double)bv.w;
    }
    __syncthreads();

    int cur = 0;
    for (int k0 = 0; k0 < K; k0 += BK) {
        const int kn = k0 + BK;
        float4 av, bv;
        if (kn < K) {                         // issue next-tile loads early
            av = *(const float4*)(Ar + kn);
            bv = *(const float4*)(Wr + (size_t)kn * N);
        }

        #pragma unroll
        for (int ks = 0; ks < 4; ++ks) {
            const int kk = (ks << 2) + l4;
            const double a0 = Asd[cur][wm + l15][kk];
            const double a1 = Asd[cur][wm + 16 + l15][kk];
            const double b0 = Bsd[cur][kk][wn + l15];
            const double b1 = Bsd[cur][kk][wn + 16 + l15];
            acc[0][0] = __builtin_amdgcn_mfma_f64_16x16x4f64(a0, b0, acc[0][0], 0, 0, 0);
            acc[0][1] = __builtin_amdgcn_mfma_f64_16x16x4f64(a0, b1, acc[0][1], 0, 0, 0);
            acc[1][0] = __builtin_amdgcn_mfma_f64_16x16x4f64(a1, b0, acc[1][0], 0, 0, 0);
            acc[1][1] = __builtin_amdgcn_mfma_f64_16x16x4f64(a1, b1, acc[1][1], 0, 0, 0);
        }

        if (kn < K) {
            const int nb = cur ^ 1;
            Asd[nb][a_r][a_c + 0] = (double)av.x;
            Asd[nb][a_r][a_c + 1] = (double)av.y;
            Asd[nb][a_r][a_c + 2] = (double)av.z;
            Asd[nb][a_r][a_c + 3] = (double)av.w;
            Bsd[nb][b_r][b_c + 0] = (double)bv.x;
            Bsd[nb][b_r][b_c + 1] = (double)bv.y;
            Bsd[nb][b_r][b_c + 2] = (double)bv.z;
            Bsd[nb][b_r][b_c + 3] = (double)bv.w;
            __syncthreads();
            cur = nb;
        }
    }

    // epilogue
    #pragma unroll
    for (int nt = 0; nt < 2; ++nt) {
        const int col = col0 + wn + (nt << 4) + l15;
        const double bb = (double)bias[col];
        #pragma unroll
        for (int mt = 0; mt < 2; ++mt) {
            #pragma unroll
            for (int g = 0; g < 4; ++g) {
                const int row = row0 + wm + (mt << 4) + (l4 << 2) + g;
                double v = acc[mt][nt][g] + bb;
                if (ACT == 1) v = fmax(v, 0.0);
                C[(size_t)row * N + col] = (float)v;
            }
        }
    }
}

// ---------------- codebook squared norms (f64) ----------------
__global__ void cnorm_kernel(const float* __restrict__ cb0, const float* __restrict__ cb1,
                             double* __restrict__ cn0, double* __restrict__ cn1)
{
    const float* cb = blockIdx.x ? cb1 : cb0;
    double* cn      = blockIdx.x ? cn1 : cn0;
    const int j = threadIdx.x;
    const float* row = cb + (size_t)j * D_LAT;
    double s = 0.0;
    #pragma unroll 8
    for (int t = 0; t < 64; ++t) {
        const float4 c = *(const float4*)(row + (t << 2));
        s = fma((double)c.x, (double)c.x, s);
        s = fma((double)c.y, (double)c.y, s);
        s = fma((double)c.z, (double)c.z, s);
        s = fma((double)c.w, (double)c.w, s);
    }
    cn[j] = s;
}

// ---------------- VQ distance GEMM pass (f64, round-0 proven 4x4) ----------------
template<bool SUB>
__global__ __launch_bounds__(256)
void vq_dots_kernel(const float* __restrict__ enc, const float* __restrict__ cbA,
                    const unsigned long long* __restrict__ key_in,
                    const float* __restrict__ cb, const double* __restrict__ cnorm,
                    unsigned long long* __restrict__ key_out)
{
    __shared__ float As[BK][BMV + 4];
    __shared__ float Bs[BK][BNV + 4];

    const int tid   = threadIdx.x;
    const int row0  = blockIdx.y * BMV;
    const int code0 = blockIdx.x * BNV;
    const int tx = tid & 15;
    const int ty = tid >> 4;
    const int a_r = tid >> 2;
    const int a_c = (tid & 3) << 2;

    double acc[4][4] = {};

    int sub_idx = 0;
    if (SUB)
        sub_idx = (int)(key_in[row0 + a_r] & 0xFFull);

    for (int k0 = 0; k0 < D_LAT; k0 += BK) {
        float4 av = *(const float4*)(enc + (size_t)(row0 + a_r) * D_LAT + (k0 + a_c));
        if (SUB) {
            const float4 qv = *(const float4*)(cbA + (size_t)sub_idx * D_LAT + (k0 + a_c));
            av.x -= qv.x; av.y -= qv.y; av.z -= qv.z; av.w -= qv.w;
        }
        As[a_c + 0][a_r] = av.x;
        As[a_c + 1][a_r] = av.y;
        As[a_c + 2][a_r] = av.z;
        As[a_c + 3][a_r] = av.w;

        const float4 bv = *(const float4*)(cb + (size_t)(code0 + a_r) * D_LAT + (k0 + a_c));
        Bs[a_c + 0][a_r] = bv.x;
        Bs[a_c + 1][a_r] = bv.y;
        Bs[a_c + 2][a_r] = bv.z;
        Bs[a_c + 3][a_r] = bv.w;

        __syncthreads();
        #pragma unroll
        for (int kk = 0; kk < BK; ++kk) {
            const float4 a = *(const float4*)&As[kk][ty << 2];
            const float4 b = *(const float4*)&Bs[kk][tx << 2];
            const double ar[4] = {(double)a.x, (double)a.y, (double)a.z, (double)a.w};
            const double br[4] = {(double)b.x, (double)b.y, (double)b.z, (double)b.w};
            #pragma unroll
            for (int i = 0; i < 4; ++i)
                #pragma unroll
                for (int j = 0; j < 4; ++j)
                    acc[i][j] = fma(ar[i], br[j], acc[i][j]);
        }
        __syncthreads();
    }

    unsigned long long kmin[4];
    #pragma unroll
    for (int i = 0; i < 4; ++i) {
        kmin[i] = 0xFFFFFFFFFFFFFFFFull;
        #pragma unroll
        for (int j = 0; j < 4; ++j) {
            const int code = code0 + (tx << 2) + j;
            const double d = cnorm[code] - 2.0 * acc[i][j];
            const unsigned long long k = enc_key(d, code);
            if (k < kmin[i]) kmin[i] = k;
        }
    }
    #pragma unroll
    for (int off = 1; off < 16; off <<= 1) {
        #pragma unroll
        for (int i = 0; i < 4; ++i) {
            const unsigned long long o = __shfl_xor(kmin[i], off, 64);
            if (o < kmin[i]) kmin[i] = o;
        }
    }
    if (tx == 0) {
        #pragma unroll
        for (int i = 0; i < 4; ++i)
            atomicMin(key_out + row0 + (ty << 2) + i, kmin[i]);
    }
}

// ---------------- f32 GEMM (decoder path), 8x8, double-buffered ----------------
// cols per thread are STRIDED (c = col0 + j*16 + tx) -> B-fragment scalar reads
// are 16-lane broadcasts across distinct banks; coalesced C stores.
template<int ACT, bool FUSE_LOSS>   // ACT: 0=none,1=relu,2=tanh
__global__ __launch_bounds__(256)
void gemm_kernel(const float* __restrict__ A, const float* __restrict__ W,
                 const float* __restrict__ bias, float* __restrict__ C,
                 const float* __restrict__ X, float* __restrict__ loss_acc,
                 int M, int N, int K)
{
    __shared__ float As[2][BK][BM32 + 4];
    __shared__ float Bs[2][BK][BN32 + 4];
    __shared__ float wsum[4];

    const int tid  = threadIdx.x;
    const int row0 = blockIdx.y * BM32;
    const int col0 = blockIdx.x * BN32;
    const int tx = tid & 15;
    const int ty = tid >> 4;

    const int a_r = tid >> 2;
    const int a_c = (tid & 3) << 2;
    const int b_r = tid >> 4;            // k 0..15
    const int b_c = (tid & 15) << 3;     // n offset, 8 floats per thread

    const float* Arow0 = A + (size_t)(row0 + a_r) * K + a_c;
    const float* Arow1 = A + (size_t)(row0 + 64 + a_r) * K + a_c;

    float acc[8][8] = {};

    auto loadB = [&](int k, float4& b0, float4& b1) {
        const int gc = col0 + b_c;
        const float* Wr = W + (size_t)(k + b_r) * N + gc;
        if (gc + 7 < N) {
            b0 = *(const float4*)(Wr);
            b1 = *(const float4*)(Wr + 4);
        } else {
            float t[8];
            #pragma unroll
            for (int u = 0; u < 8; ++u) t[u] = (gc + u < N) ? Wr[u] : 0.f;
            b0 = make_float4(t[0], t[1], t[2], t[3]);
            b1 = make_float4(t[4], t[5], t[6], t[7]);
        }
    };

    // prologue
    {
        const float4 av0 = *(const float4*)(Arow0);
        const float4 av1 = *(const float4*)(Arow1);
        float4 bv0, bv1; loadB(0, bv0, bv1);
        As[0][a_c + 0][a_r] = av0.x; As[0][a_c + 1][a_r] = av0.y;
        As[0][a_c + 2][a_r] = av0.z; As[0][a_c + 3][a_r] = av0.w;
        As[0][a_c + 0][64 + a_r] = av1.x; As[0][a_c + 1][64 + a_r] = av1.y;
        As[0][a_c + 2][64 + a_r] = av1.z; As[0][a_c + 3][64 + a_r] = av1.w;
        *(float4*)&Bs[0][b_r][b_c] = bv0;
        *(float4*)&Bs[0][b_r][b_c + 4] = bv1;
    }
    __syncthreads();

    int cur = 0;
    for (int k0 = 0; k0 < K; k0 += BK) {
        const int kn = k0 + BK;
        float4 av0, av1, bv0, bv1;
        if (kn < K) {
            av0 = *(const float4*)(Arow0 + kn);
            av1 = *(const float4*)(Arow1 + kn);
            loadB(kn, bv0, bv1);
        }

        #pragma unroll
        for (int kk = 0; kk < BK; ++kk) {
            const float4 a0 = *(const float4*)&As[cur][kk][ty << 3];
            const float4 a1 = *(const float4*)&As[cur][kk][(ty << 3) + 4];
            const float ar[8] = {a0.x, a0.y, a0.z, a0.w, a1.x, a1.y, a1.z, a1.w};
            float br[8];
            #pragma unroll
            for (int j = 0; j < 8; ++j)
                br[j] = Bs[cur][kk][(j << 4) + tx];
            #pragma unroll
            for (int i = 0; i < 8; ++i)
                #pragma unroll
                for (int j = 0; j < 8; ++j)
                    acc[i][j] = fmaf(ar[i], br[j], acc[i][j]);
        }

        if (kn < K) {
            const int nb = cur ^ 1;
            As[nb][a_c + 0][a_r] = av0.x; As[nb][a_c + 1][a_r] = av0.y;
            As[nb][a_c + 2][a_r] = av0.z; As[nb][a_c + 3][a_r] = av0.w;
            As[nb][a_c + 0][64 + a_r] = av1.x; As[nb][a_c + 1][64 + a_r] = av1.y;
            As[nb][a_c + 2][64 + a_r] = av1.z; As[nb][a_c + 3][64 + a_r] = av1.w;
            *(float4*)&Bs[nb][b_r][b_c] = bv0;
            *(float4*)&Bs[nb][b_r][b_c + 4] = bv1;
            __syncthreads();
            cur = nb;
        }
    }

    // epilogue
    float bb[8];
    #pragma unroll
    for (int j = 0; j < 8; ++j) {
        const int c = col0 + (j << 4) + tx;
        bb[j] = (c < N) ? bias[c] : 0.f;
    }

    float lsum = 0.f;
    #pragma unroll
    for (int i = 0; i < 8; ++i) {
        const int r = row0 + (ty << 3) + i;
        #pragma unroll
        for (int j = 0; j < 8; ++j) {
            const int c = col0 + (j << 4) + tx;
            if (c < N) {
                float v = acc[i][j] + bb[j];
                if (ACT == 1) v = fmaxf(v, 0.f);
                if (ACT == 2) v = tanhf(v);
                C[(size_t)r * N + c] = v;
                if (FUSE_LOSS) {
                    const float d = v - X[(size_t)r * N + c];
                    lsum = fmaf(d, d, lsum);
                }
            }
        }
    }

    if (FUSE_LOSS) {
        #pragma unroll
        for (int off = 32; off > 0; off >>= 1)
            lsum += __shfl_xor(lsum, off, 64);
        if ((tid & 63) == 0) wsum[tid >> 6] = lsum;
        __syncthreads();
        if (tid == 0)
            atomicAdd(loss_acc, wsum[0] + wsum[1] + wsum[2] + wsum[3]);
    }
}

// ---------------- VQ finalize: indices, commit, quantized ----------------
__global__ __launch_bounds__(256)
void vq_finalize_kernel(float* __restrict__ encq,
                        const float* __restrict__ cb0, const float* __restrict__ cb1,
                        const unsigned long long* __restrict__ key0,
                        const unsigned long long* __restrict__ key1,
                        float* __restrict__ idx_out, float* __restrict__ commit_acc)
{
    __shared__ float csum[4];
    const int wave = threadIdx.x >> 6;
    const int lane = threadIdx.x & 63;
    const int row  = (blockIdx.x << 2) + wave;

    const unsigned long long k0 = key0[row];
    const unsigned long long k1 = key1[row];
    const int i0 = (int)(k0 & 0xFFull);
    const int i1 = (int)(k1 & 0xFFull);

    const float4 e = *(const float4*)(encq + (size_t)row * D_LAT + (lane << 2));
    float nrm = 0.f;
    nrm = fmaf(e.x, e.x, nrm); nrm = fmaf(e.y, e.y, nrm);
    nrm = fmaf(e.z, e.z, nrm); nrm = fmaf(e.w, e.w, nrm);
    #pragma unroll
    for (int off = 32; off > 0; off >>= 1)
        nrm += __shfl_xor(nrm, off, 64);

    const float4 q0 = *(const float4*)(cb0 + (size_t)i0 * D_LAT + (lane << 2));
    const float4 q1 = *(const float4*)(cb1 + (size_t)i1 * D_LAT + (lane << 2));
    const float4 q = make_float4(q0.x + q1.x, q0.y + q1.y, q0.z + q1.z, q0.w + q1.w);
    *(float4*)(encq + (size_t)row * D_LAT + (lane << 2)) = q;

    if (lane == 0) {
        idx_out[(size_t)row * 2 + 0] = (float)i0;
        idx_out[(size_t)row * 2 + 1] = (float)i1;
        const float d0 = (float)dec_key(k0);
        const float d1 = (float)dec_key(k1);
        csum[wave] = 2.f * (nrm + d0) + d1;
    }
    __syncthreads();
    if (threadIdx.x == 0)
        atomicAdd(commit_acc, csum[0] + csum[1] + csum[2] + csum[3]);
}

__global__ void finalize_kernel(const float* __restrict__ acc, float* __restrict__ out_loss)
{
    const float recon_loss  = acc[0] / (float)((size_t)B_ROWS * D_IN);
    const float commit_loss = 0.25f * acc[1] / (float)((size_t)B_ROWS * D_LAT);
    *out_loss = recon_loss + commit_loss;
}

extern "C" void kernel_launch(void* const* d_in, const int* in_sizes, int n_in,
                              void* d_out, int out_size, void* d_ws, size_t ws_size,
                              hipStream_t stream)
{
    const float* x   = (const float*)d_in[0];
    const float* We1 = (const float*)d_in[1];
    const float* be1 = (const float*)d_in[2];
    const float* We2 = (const float*)d_in[3];
    const float* be2 = (const float*)d_in[4];
    const float* cb0 = (const float*)d_in[5];
    const float* cb1 = (const float*)d_in[6];
    const float* Wd1 = (const float*)d_in[7];
    const float* bd1 = (const float*)d_in[8];
    const float* Wd2 = (const float*)d_in[9];
    const float* bd2 = (const float*)d_in[10];

    float* out      = (float*)d_out;
    float* recon    = out;                                   // B*784
    float* idx_out  = out + (size_t)B_ROWS * D_IN;           // B*2 (as float)
    float* loss_out = idx_out + (size_t)B_ROWS * 2;          // 1

    // ws layout
    char* w = (char*)d_ws;
    float* h = (float*)w;                    w += (size_t)B_ROWS * D_HID * sizeof(float);
    float* acc = (float*)w;                  w += 16;
    unsigned long long* key0 = (unsigned long long*)w;  w += (size_t)B_ROWS * 8;
    unsigned long long* key1 = (unsigned long long*)w;  w += (size_t)B_ROWS * 8;
    double* cn0 = (double*)w;                w += N_CODES * sizeof(double);
    double* cn1 = (double*)w;                w += N_CODES * sizeof(double);

    // enc/quantized live in the recon region of d_out (dead before recon write)
    float* encq = recon;

    hipMemsetAsync(acc, 0, 2 * sizeof(float), stream);
    hipMemsetAsync(key0, 0xFF, (size_t)B_ROWS * 16, stream);   // key0 + key1

    const dim3 blk(256);
    // codebook norms (f64)
    cnorm_kernel<<<dim3(2), blk, 0, stream>>>(cb0, cb1, cn0, cn1);
    // encoder 1 (f64 MFMA): relu(x @ We1 + be1) -> h
    gemm_f64_mfma_kernel<1><<<dim3(D_HID / 64, B_ROWS / 64), blk, 0, stream>>>(
        x, We1, be1, h, B_ROWS, D_HID, D_IN);
    // encoder 2 (f64 MFMA): h @ We2 + be2 -> enc
    gemm_f64_mfma_kernel<0><<<dim3(D_LAT / 64, B_ROWS / 64), blk, 0, stream>>>(
        h, We2, be2, encq, B_ROWS, D_LAT, D_HID);
    // VQ stage 1: distances to cb0, per-row argmin via u64 atomicMin
    vq_dots_kernel<false><<<dim3(N_CODES / BNV, B_ROWS / BMV), blk, 0, stream>>>(
        encq, nullptr, nullptr, cb0, cn0, key0);
    // VQ stage 2: residual (enc - cb0[i0]) vs cb1
    vq_dots_kernel<true><<<dim3(N_CODES / BNV, B_ROWS / BMV), blk, 0, stream>>>(
        encq, cb0, key0, cb1, cn1, key1);
    // finalize: indices, commit partials, quantized (in place)
    vq_finalize_kernel<<<dim3(B_ROWS / 4), blk, 0, stream>>>(
        encq, cb0, cb1, key0, key1, idx_out, acc + 1);
    // decoder 1 (f32): relu(quantized @ Wd1 + bd1) -> h
    gemm_kernel<1, false><<<dim3(D_HID / BN32, B_ROWS / BM32), blk, 0, stream>>>(
        encq, Wd1, bd1, h, nullptr, nullptr, B_ROWS, D_HID, D_LAT);
    // decoder 2 (f32): tanh(h @ Wd2 + bd2) -> recon, fused MSE partials
    gemm_kernel<2, true><<<dim3((D_IN + BN32 - 1) / BN32, B_ROWS / BM32), blk, 0, stream>>>(
        h, Wd2, bd2, recon, x, acc + 0, B_ROWS, D_IN, D_HID);
    finalize_kernel<<<1, 1, 0, stream>>>(acc, loss_out);
}